// Round 1
// baseline (163.390 us; speedup 1.0000x reference)
//
#include <hip/hip_runtime.h>
#include <stdint.h>
#include <math.h>

#define HH 256
#define WW 256
#define BATCH 16
#define HP 257
#define SROW 264            // padded row stride for s
#define SB (HP*SROW)        // per-batch s size (floats)
#define NPIX (HP*HP)        // 66049

__device__ __forceinline__ float leaky(float v){ return v >= 0.f ? v : 0.01f*v; }

__device__ __forceinline__ unsigned fkey(float f){
    unsigned u = __float_as_uint(f);
    return (u & 0x80000000u) ? ~u : (u | 0x80000000u);
}
__device__ __forceinline__ float funkey(unsigned k){
    return (k & 0x80000000u) ? __uint_as_float(k ^ 0x80000000u) : __uint_as_float(~k);
}

// offsets d for channel 0 of group k; channel 1 uses -d
__device__ __constant__ int D0H[4] = {-1,-1,-1,0};
__device__ __constant__ int D0W[4] = {-1, 0, 1,1};

// ---- kernel 1: s[b,h,w] = (sum_c sum_{2x2 window} x)/4, 257x257 per batch ----
__global__ void k1_pool(const float* __restrict__ x, float* __restrict__ s){
    int idx = blockIdx.x*256 + threadIdx.x;
    if (idx >= BATCH*NPIX) return;
    int b = idx / NPIX;
    int r = idx % NPIX;
    int h = r / HP, w = r % HP;
    const float* xb = x + (size_t)b*3*HH*WW;
    float acc = 0.f;
    #pragma unroll
    for (int dy=-1; dy<=0; ++dy){
        int i = h+dy; if ((unsigned)i >= HH) continue;
        #pragma unroll
        for (int dx=-1; dx<=0; ++dx){
            int j = w+dx; if ((unsigned)j >= WW) continue;
            int o = i*WW + j;
            acc += xb[o] + xb[HH*WW + o] + xb[2*HH*WW + o];
        }
    }
    s[(size_t)b*SB + h*SROW + w] = acc * 0.25f;
}

// ---- kernel 2: per (group g=b*4+k, ch 0/1) min & max of clipped xl ----
__global__ void k2_minmax(const float* __restrict__ s, const float* __restrict__ cl,
                          const float* __restrict__ chp,
                          unsigned* __restrict__ mnk, unsigned* __restrict__ mxk){
    int g = blockIdx.y;          // 0..63
    int b = g >> 2, k = g & 3;
    int dh = D0H[k], dw = D0W[k];
    float lo = cl[0], hi = chp[0];
    const float* sb = s + (size_t)b*SB;
    float mn0=INFINITY, mx0=-INFINITY, mn1=INFINITY, mx1=-INFINITY;
    for (int idx = blockIdx.x*256 + threadIdx.x; idx < NPIX; idx += gridDim.x*256){
        int h = idx / HP, w = idx % HP;
        float c = sb[h*SROW+w];
        int h0=h+dh, w0=w+dw;
        float n0 = ((unsigned)h0 < HP && (unsigned)w0 < HP) ? sb[h0*SROW+w0] : 0.f;
        int h1=h-dh, w1=w-dw;
        float n1 = ((unsigned)h1 < HP && (unsigned)w1 < HP) ? sb[h1*SROW+w1] : 0.f;
        float v0 = fminf(fmaxf(c-n0, lo), hi);
        float v1 = fminf(fmaxf(c-n1, lo), hi);
        mn0 = fminf(mn0,v0); mx0 = fmaxf(mx0,v0);
        mn1 = fminf(mn1,v1); mx1 = fmaxf(mx1,v1);
    }
    #pragma unroll
    for (int off=32; off; off>>=1){
        mn0 = fminf(mn0, __shfl_down(mn0, off));
        mx0 = fmaxf(mx0, __shfl_down(mx0, off));
        mn1 = fminf(mn1, __shfl_down(mn1, off));
        mx1 = fmaxf(mx1, __shfl_down(mx1, off));
    }
    if ((threadIdx.x & 63) == 0){
        atomicMin(&mnk[g*2+0], fkey(mn0));
        atomicMax(&mxk[g*2+0], fkey(mx0));
        atomicMin(&mnk[g*2+1], fkey(mn1));
        atomicMax(&mxk[g*2+1], fkey(mx1));
    }
}

// ---- kernel 3: joint histogram of masked-value products ----
__global__ void k3_hist(const float* __restrict__ s, const float* __restrict__ cl,
                        const float* __restrict__ chp,
                        const unsigned* __restrict__ mnk, const unsigned* __restrict__ mxk,
                        float* __restrict__ hist){
    __shared__ float lh[8*64];
    int g = blockIdx.y; int b = g>>2, k = g&3;
    int dh = D0H[k], dw = D0W[k];
    float lo = cl[0], hi = chp[0];
    float mn0 = funkey(mnk[g*2+0]), mx0 = funkey(mxk[g*2+0]);
    float mn1 = funkey(mnk[g*2+1]), mx1 = funkey(mxk[g*2+1]);
    float cd0 = (mx0-mn0)*0.125f;      // == (mx-mn)/8, exact pow2 scale
    float cd1 = (mx1-mn1)*0.125f;
    float m0[9], m1[9];
    #pragma unroll
    for (int i=0;i<9;i++){
        m0[i] = __fadd_rn(__fmul_rn((float)i, cd0), mn0);   // match ref: mul then add, no fma
        m1[i] = __fadd_rn(__fmul_rn((float)i, cd1), mn1);
    }
    for (int t=threadIdx.x; t<512; t+=256) lh[t]=0.f;
    __syncthreads();
    const float* sb = s + (size_t)b*SB;
    int repl = (threadIdx.x & 7) * 64;
    for (int idx = blockIdx.x*256 + threadIdx.x; idx < NPIX; idx += gridDim.x*256){
        int h = idx/HP, w = idx%HP;
        float c = sb[h*SROW+w];
        int h0=h+dh, w0=w+dw;
        float n0 = ((unsigned)h0<HP && (unsigned)w0<HP) ? sb[h0*SROW+w0] : 0.f;
        int h1=h-dh, w1=w-dw;
        float n1 = ((unsigned)h1<HP && (unsigned)w1<HP) ? sb[h1*SROW+w1] : 0.f;
        float v0 = fminf(fmaxf(c-n0, lo), hi);
        float v1 = fminf(fmaxf(c-n1, lo), hi);
        unsigned b0=0, b1=0;
        #pragma unroll
        for (int i=0;i<8;i++){
            b0 |= (v0>=m0[i] && v0<=m0[i+1]) ? (1u<<i) : 0u;   // boundary values hit 2 bins, like ref
            b1 |= (v1>=m1[i] && v1<=m1[i+1]) ? (1u<<i) : 0u;
        }
        float p = v0*v1;
        unsigned bb0=b0;
        while (bb0){
            int i = __ffs(bb0)-1; bb0 &= bb0-1;
            unsigned bb1=b1;
            while (bb1){
                int j = __ffs(bb1)-1; bb1 &= bb1-1;
                atomicAdd(&lh[repl + i*8 + j], p);
            }
        }
    }
    __syncthreads();
    if (threadIdx.x < 64){
        float acc=0.f;
        #pragma unroll
        for (int r=0;r<8;r++) acc += lh[r*64+threadIdx.x];
        atomicAdd(&hist[g*64+threadIdx.x], acc);
    }
}

// ---- kernel 4a: per group: feat -> expand -> leaky -> h_small; weighted LN stats ----
__global__ void k4a(const float* __restrict__ hist,
                    const unsigned* __restrict__ mnk, const unsigned* __restrict__ mxk,
                    const float* __restrict__ we, const float* __restrict__ be,
                    float* __restrict__ hsm, float* __restrict__ stats){
    __shared__ float hloc[3584];
    __shared__ float sred[4];
    int g = blockIdx.x;    // 0..63
    int tid = threadIdx.x;
    // global sum of hist (redundant per block, 16KB from L2)
    float ps = 0.f;
    for (int t=tid; t<4096; t+=256) ps += hist[t];
    #pragma unroll
    for (int off=32; off; off>>=1) ps += __shfl_down(ps, off);
    if ((tid&63)==0) sred[tid>>6] = ps;
    __syncthreads();
    float S = sred[0]+sred[1]+sred[2]+sred[3];

    float mn0 = funkey(mnk[g*2+0]), mx0 = funkey(mxk[g*2+0]);
    float mn1 = funkey(mnk[g*2+1]), mx1 = funkey(mxk[g*2+1]);
    float lvl0 = __fadd_rn((mx0-mn0)*0.125f, mn0);   // measure[:,1,0]
    float lvl1 = __fadd_rn((mx1-mn1)*0.125f, mn1);   // measure[:,1,1]

    for (int e=tid; e<3584; e+=256){
        int ij = e/56, o = e%56;
        int i = ij>>3, j = ij&7;
        float f0 = __fmul_rn((float)(i+1), lvl0);
        float f1 = __fmul_rn((float)(j+1), lvl1);
        float f2 = hist[g*64+ij] / S;
        float a = f0*we[o*3+0] + f1*we[o*3+1] + f2*we[o*3+2] + be[o];
        a = leaky(a);
        hloc[e] = a;
        hsm[(size_t)g*3584 + e] = a;
    }
    __syncthreads();   // hloc ready; also separates S read from sred rewrite

    // weighted mean over upsampled grid: row weight 4, col weight cnt[o]
    float pm = 0.f;
    for (int e=tid; e<3584; e+=256){
        int o = e%56;
        int lo_ = (32*o+6)/7, hi_ = (32*o+31)/7;
        float wgt = (float)(4*(hi_-lo_+1));
        pm += hloc[e]*wgt;
    }
    #pragma unroll
    for (int off=32; off; off>>=1) pm += __shfl_down(pm, off);
    if ((tid&63)==0) sred[tid>>6]=pm;
    __syncthreads();
    float mean = (sred[0]+sred[1]+sred[2]+sred[3]) * (1.0f/65536.0f);
    __syncthreads();
    float pv = 0.f;
    for (int e=tid; e<3584; e+=256){
        int o = e%56;
        int lo_ = (32*o+6)/7, hi_ = (32*o+31)/7;
        float wgt = (float)(4*(hi_-lo_+1));
        float d = hloc[e]-mean;
        pv += d*d*wgt;
    }
    #pragma unroll
    for (int off=32; off; off>>=1) pv += __shfl_down(pv, off);
    if ((tid&63)==0) sred[tid>>6]=pv;
    __syncthreads();
    float var = (sred[0]+sred[1]+sred[2]+sred[3]) * (1.0f/65536.0f);
    if (tid==0){
        stats[g*2+0] = mean;
        stats[g*2+1] = 1.0f / sqrtf(var + 1e-5f);
    }
}

// ---- kernel 4b: layernorm + w_conv + leaky -> hconv_small [b][ij][o][c16] ----
__global__ void k4b(const float* __restrict__ hsm, const float* __restrict__ stats,
                    const float* __restrict__ wc, const float* __restrict__ bc,
                    float* __restrict__ hcv){
    int idx = blockIdx.x*256+threadIdx.x;
    if (idx >= 16*64*56*16) return;
    int c = idx & 15;
    int t = idx >> 4;
    int o = t % 56; t /= 56;
    int ij = t & 63; int b = t >> 6;
    float acc = bc[c];
    #pragma unroll
    for (int k=0;k<4;k++){
        int g = b*4+k;
        float hv = hsm[(size_t)g*3584 + ij*56 + o];
        float hn = (hv - stats[g*2])*stats[g*2+1];
        acc += wc[c*4+k]*hn;
    }
    hcv[idx] = leaky(acc);
}

// ---- kernel 5a: vertical+channel fold of final conv: F[b][y][dx][s] ----
__global__ void k5a(const float* __restrict__ hcv, const float* __restrict__ wf,
                    float* __restrict__ F){
    __shared__ float wfl[144];
    if (threadIdx.x < 144) wfl[threadIdx.x] = wf[threadIdx.x];
    __syncthreads();
    int idx = blockIdx.x*256+threadIdx.x;
    if (idx >= 16*256*56) return;
    int sxc = idx % 56;
    int y = (idx/56) & 255;
    int b = idx / (56*256);
    float f0=0.f, f1=0.f, f2=0.f;
    #pragma unroll
    for (int dy=0; dy<3; ++dy){
        int yy = y + dy - 1;
        if ((unsigned)yy >= 256) continue;   // zero pad rows
        int r = yy >> 2;
        const float* hc = hcv + (((size_t)b*64 + r)*56 + sxc)*16;
        #pragma unroll
        for (int c=0;c<16;c++){
            float hv = hc[c];
            f0 += wfl[c*9 + dy*3 + 0]*hv;
            f1 += wfl[c*9 + dy*3 + 1]*hv;
            f2 += wfl[c*9 + dy*3 + 2]*hv;
        }
    }
    float* Fb = F + (((size_t)b*256 + y)*3)*56;
    Fb[0*56+sxc]=f0; Fb[1*56+sxc]=f1; Fb[2*56+sxc]=f2;
}

// ---- kernel 5b: horizontal gather + bias + leaky -> out ----
__global__ void k5b(const float* __restrict__ F, const float* __restrict__ bf,
                    float* __restrict__ out){
    int idx = blockIdx.x*256+threadIdx.x;
    if (idx >= 16*256*256) return;
    int x = idx & 255;
    int y = (idx >> 8) & 255;
    int b = idx >> 16;
    float acc = bf[0];
    const float* Fb = F + ((size_t)b*256 + y)*3*56;
    #pragma unroll
    for (int dx=0; dx<3; ++dx){
        int xx = x + dx - 1;
        if ((unsigned)xx >= 256) continue;   // zero pad cols
        int sxx = (xx*7) >> 5;               // arange(256)*56//256
        acc += Fb[dx*56 + sxx];
    }
    out[idx] = leaky(acc);
}

extern "C" void kernel_launch(void* const* d_in, const int* in_sizes, int n_in,
                              void* d_out, int out_size, void* d_ws, size_t ws_size,
                              hipStream_t stream){
    const float* x  = (const float*)d_in[0];
    const float* cl = (const float*)d_in[1];
    const float* ch = (const float*)d_in[2];
    const float* we = (const float*)d_in[3];
    const float* be = (const float*)d_in[4];
    const float* wc = (const float*)d_in[5];
    const float* bc = (const float*)d_in[6];
    const float* wf = (const float*)d_in[7];
    const float* bf = (const float*)d_in[8];
    float* out = (float*)d_out;

    float* s = (float*)d_ws;                              // 16*SB floats
    size_t off = (size_t)16*SB;
    unsigned* mnk = (unsigned*)(s + off); off += 128;
    unsigned* mxk = (unsigned*)(s + off); off += 128;
    float* hist = s + off; off += 4096;
    float* hsm  = s + off; off += 229376;
    float* stats= s + off; off += 128;
    float* hcv  = s + off; off += 917504;
    float* F    = s;   // alias: s is dead after k3, F written in k5a

    hipMemsetAsync(mnk, 0xFF, 128*4, stream);   // min keys -> max uint
    hipMemsetAsync(mxk, 0x00, 128*4, stream);   // max keys -> 0
    hipMemsetAsync(hist, 0, 4096*4, stream);

    k1_pool<<<dim3((BATCH*NPIX+255)/256), 256, 0, stream>>>(x, s);
    k2_minmax<<<dim3(8,64), 256, 0, stream>>>(s, cl, ch, mnk, mxk);
    k3_hist<<<dim3(16,64), 256, 0, stream>>>(s, cl, ch, mnk, mxk, hist);
    k4a<<<64, 256, 0, stream>>>(hist, mnk, mxk, we, be, hsm, stats);
    k4b<<<(16*64*56*16+255)/256, 256, 0, stream>>>(hsm, stats, wc, bc, hcv);
    k5a<<<(16*256*56+255)/256, 256, 0, stream>>>(hcv, wf, F);
    k5b<<<(16*256*256+255)/256, 256, 0, stream>>>(F, bf, out);
}

// Round 3
// 162.481 us; speedup vs baseline: 1.0056x; 1.0056x over previous
//
#include <hip/hip_runtime.h>
#include <stdint.h>
#include <math.h>

#define HH 256
#define WW 256
#define BATCH 16
#define HP 257            // pooled field is 257x257
#define SROW 264          // padded row stride
#define SH 259            // padded rows (1 zero row top/bottom)
#define SBP (SH*SROW)     // per-batch padded s size = 68376 floats
#define NPIX (HP*HP)      // 66049

__device__ __forceinline__ float leaky(float v){ return v >= 0.f ? v : 0.01f*v; }

__device__ __forceinline__ unsigned fkey(float f){
    unsigned u = __float_as_uint(f);
    return (u & 0x80000000u) ? ~u : (u | 0x80000000u);
}
__device__ __forceinline__ float funkey(unsigned k){
    return (k & 0x80000000u) ? __uint_as_float(k ^ 0x80000000u) : __uint_as_float(~k);
}

// group k (0..3) channel-0 offset; channel 1 uses the negation.
__device__ __forceinline__ void group_off(int k, int& dh, int& dw){
    dh = (k == 3) ? 0 : -1;
    dw = (k == 3) ? 1 : (k - 1);
}

// ---- kernel 1: s_pad[b,ph,pw]; interior = (sum_c 2x2 avgpool)/4, border = 0.
//      block 0 also zero-inits mnk/mxk/hist (stream order => visible to k2/k3). ----
__global__ __launch_bounds__(256) void k1_pool(const float* __restrict__ x, float* __restrict__ s,
                                               unsigned* __restrict__ mnk, unsigned* __restrict__ mxk,
                                               float* __restrict__ hist){
    if (blockIdx.x == 0){
        if (threadIdx.x < 128){ mnk[threadIdx.x] = 0xFFFFFFFFu; mxk[threadIdx.x] = 0u; }
        for (int t = threadIdx.x; t < 4096; t += 256) hist[t] = 0.f;
    }
    int idx = blockIdx.x*256 + threadIdx.x;
    if (idx >= BATCH*SBP) return;
    int b = idx / SBP;
    int r = idx % SBP;
    int ph = r / SROW, pw = r % SROW;
    int h = ph - 1, w = pw - 1;
    float val = 0.f;
    if ((unsigned)h < (unsigned)HP && (unsigned)w < (unsigned)HP){
        const float* xb = x + (size_t)b*3*HH*WW;
        float acc = 0.f;
        #pragma unroll
        for (int dy=-1; dy<=0; ++dy){
            int i = h+dy; if ((unsigned)i >= HH) continue;
            #pragma unroll
            for (int dx=-1; dx<=0; ++dx){
                int j = w+dx; if ((unsigned)j >= WW) continue;
                int o = i*WW + j;
                acc += xb[o] + xb[HH*WW + o] + xb[2*HH*WW + o];
            }
        }
        val = acc * 0.25f;
    }
    s[idx] = val;
}

// ---- kernel 2: min/max per (batch, group, channel). Wave wv handles group wv. ----
__global__ __launch_bounds__(256) void k2_minmax(const float* __restrict__ s, const float* __restrict__ cl,
                                                 const float* __restrict__ chp,
                                                 unsigned* __restrict__ mnk, unsigned* __restrict__ mxk){
    int b = blockIdx.y;
    int wv = threadIdx.x >> 6, lane = threadIdx.x & 63;
    int dh, dw; group_off(wv, dh, dw);
    int doff = dh*SROW + dw;
    float lo = cl[0], hi = chp[0];
    const float* sp = s + (size_t)b*SBP + SROW + 1;
    float mn0=INFINITY, mx0=-INFINITY, mn1=INFINITY, mx1=-INFINITY;
    for (int idx = blockIdx.x*64 + lane; idx < NPIX; idx += gridDim.x*64){
        int h = idx / HP, w = idx - h*HP;
        const float* p = sp + h*SROW + w;
        float c = p[0];
        float v0 = fminf(fmaxf(c - p[doff],  lo), hi);
        float v1 = fminf(fmaxf(c - p[-doff], lo), hi);
        mn0 = fminf(mn0,v0); mx0 = fmaxf(mx0,v0);
        mn1 = fminf(mn1,v1); mx1 = fmaxf(mx1,v1);
    }
    #pragma unroll
    for (int off=32; off; off>>=1){
        mn0 = fminf(mn0, __shfl_down(mn0, off));
        mx0 = fmaxf(mx0, __shfl_down(mx0, off));
        mn1 = fminf(mn1, __shfl_down(mn1, off));
        mx1 = fmaxf(mx1, __shfl_down(mx1, off));
    }
    if (lane == 0){
        int g = b*4 + wv;
        atomicMin(&mnk[g*2+0], fkey(mn0));
        atomicMax(&mxk[g*2+0], fkey(mx0));
        atomicMin(&mnk[g*2+1], fkey(mn1));
        atomicMax(&mxk[g*2+1], fkey(mx1));
    }
}

// ---- kernel 3: joint histogram. Wave wv handles group wv; 8 LDS replicas/group. ----
__global__ __launch_bounds__(256) void k3_hist(const float* __restrict__ s, const float* __restrict__ cl,
                                               const float* __restrict__ chp,
                                               const unsigned* __restrict__ mnk, const unsigned* __restrict__ mxk,
                                               float* __restrict__ hist){
    __shared__ float lh[4*64*8];   // [group][bin][replica]
    int b = blockIdx.y;
    int wv = threadIdx.x >> 6, lane = threadIdx.x & 63;
    for (int t = threadIdx.x; t < 2048; t += 256) lh[t] = 0.f;
    __syncthreads();
    int g = b*4 + wv;
    float lo = cl[0], hi = chp[0];
    float mn0 = funkey(mnk[g*2+0]), mx0 = funkey(mxk[g*2+0]);
    float mn1 = funkey(mnk[g*2+1]), mx1 = funkey(mxk[g*2+1]);
    float cd0 = (mx0-mn0)*0.125f;
    float cd1 = (mx1-mn1)*0.125f;
    float m0[9], m1[9];
    #pragma unroll
    for (int i=0;i<9;i++){
        m0[i] = __fadd_rn(__fmul_rn((float)i, cd0), mn0);   // match ref: mul then add, no fma
        m1[i] = __fadd_rn(__fmul_rn((float)i, cd1), mn1);
    }
    int dh, dw; group_off(wv, dh, dw);
    int doff = dh*SROW + dw;
    const float* sp = s + (size_t)b*SBP + SROW + 1;
    float* lhg = lh + wv*512 + (lane & 7);
    for (int idx = blockIdx.x*64 + lane; idx < NPIX; idx += gridDim.x*64){
        int h = idx / HP, w = idx - h*HP;
        const float* p = sp + h*SROW + w;
        float c = p[0];
        float v0 = fminf(fmaxf(c - p[doff],  lo), hi);
        float v1 = fminf(fmaxf(c - p[-doff], lo), hi);
        unsigned b0=0, b1=0;
        #pragma unroll
        for (int i=0;i<8;i++){
            b0 |= (v0>=m0[i] && v0<=m0[i+1]) ? (1u<<i) : 0u;  // boundary values hit 2 bins, like ref
            b1 |= (v1>=m1[i] && v1<=m1[i+1]) ? (1u<<i) : 0u;
        }
        float pr = v0*v1;
        unsigned bb0=b0;
        while (bb0){
            int i = __ffs(bb0)-1; bb0 &= bb0-1;
            unsigned bb1=b1;
            while (bb1){
                int j = __ffs(bb1)-1; bb1 &= bb1-1;
                atomicAdd(&lhg[(i*8+j)*8], pr);
            }
        }
    }
    __syncthreads();
    int gg = threadIdx.x >> 6, bin = threadIdx.x & 63;   // 256 threads = 4x64
    float acc = 0.f;
    #pragma unroll
    for (int r=0;r<8;r++) acc += lh[gg*512 + bin*8 + r];
    atomicAdd(&hist[(b*4+gg)*64 + bin], acc);
}

// ---- kernel 4a: per group (block): hist-sum, expand+leaky -> hsm; weighted LN stats ----
__global__ __launch_bounds__(256) void k4a(const float* __restrict__ hist,
                    const unsigned* __restrict__ mnk, const unsigned* __restrict__ mxk,
                    const float* __restrict__ we, const float* __restrict__ be,
                    float* __restrict__ hsm, float* __restrict__ stats){
    __shared__ float hloc[3584];
    __shared__ float sred[4];
    int g = blockIdx.x;    // 0..63
    int tid = threadIdx.x;
    // global sum of hist (redundant per block, 16KB from L2)
    float ps = 0.f;
    for (int t=tid; t<4096; t+=256) ps += hist[t];
    #pragma unroll
    for (int off=32; off; off>>=1) ps += __shfl_down(ps, off);
    if ((tid&63)==0) sred[tid>>6] = ps;
    __syncthreads();
    float S = sred[0]+sred[1]+sred[2]+sred[3];

    float mn0 = funkey(mnk[g*2+0]), mx0 = funkey(mxk[g*2+0]);
    float mn1 = funkey(mnk[g*2+1]), mx1 = funkey(mxk[g*2+1]);
    float lvl0 = __fadd_rn(__fmul_rn(1.0f,(mx0-mn0)*0.125f), mn0);   // measure[:,1,0]
    float lvl1 = __fadd_rn(__fmul_rn(1.0f,(mx1-mn1)*0.125f), mn1);

    for (int e=tid; e<3584; e+=256){
        int ij = e/56, o = e%56;
        int i = ij>>3, j = ij&7;
        float f0 = __fmul_rn((float)(i+1), lvl0);
        float f1 = __fmul_rn((float)(j+1), lvl1);
        float f2 = hist[g*64+ij] / S;
        float a = f0*we[o*3+0] + f1*we[o*3+1] + f2*we[o*3+2] + be[o];
        a = leaky(a);
        hloc[e] = a;
        hsm[(size_t)g*3584 + e] = a;
    }
    __syncthreads();

    // weighted mean over upsampled grid: row weight 4, col weight cnt[o]
    float pm = 0.f;
    for (int e=tid; e<3584; e+=256){
        int o = e%56;
        int lo_ = (32*o+6)/7, hi_ = (32*o+31)/7;
        float wgt = (float)(4*(hi_-lo_+1));
        pm += hloc[e]*wgt;
    }
    #pragma unroll
    for (int off=32; off; off>>=1) pm += __shfl_down(pm, off);
    if ((tid&63)==0) sred[tid>>6]=pm;
    __syncthreads();
    float mean = (sred[0]+sred[1]+sred[2]+sred[3]) * (1.0f/65536.0f);
    __syncthreads();
    float pv = 0.f;
    for (int e=tid; e<3584; e+=256){
        int o = e%56;
        int lo_ = (32*o+6)/7, hi_ = (32*o+31)/7;
        float wgt = (float)(4*(hi_-lo_+1));
        float d = hloc[e]-mean;
        pv += d*d*wgt;
    }
    #pragma unroll
    for (int off=32; off; off>>=1) pv += __shfl_down(pv, off);
    if ((tid&63)==0) sred[tid>>6]=pv;
    __syncthreads();
    float var = (sred[0]+sred[1]+sred[2]+sred[3]) * (1.0f/65536.0f);
    if (tid==0){
        stats[g*2+0] = mean;
        stats[g*2+1] = 1.0f / sqrtf(var + 1e-5f);
    }
}

// ---- kernel 4w: LN + w_conv + leaky + fold with w_final -> w9[b][r][dy*3+dx][s] ----
__global__ __launch_bounds__(256) void k4w(const float* __restrict__ hsm, const float* __restrict__ stats,
                                           const float* __restrict__ wc, const float* __restrict__ bc,
                                           const float* __restrict__ wf,
                                           float* __restrict__ w9g){
    __shared__ float wfl[144];
    if (threadIdx.x < 144) wfl[threadIdx.x] = wf[threadIdx.x];
    __syncthreads();
    int idx = blockIdx.x*256 + threadIdx.x;
    if (idx >= 16*64*56) return;
    int sxc = idx % 56;
    int r = (idx/56) & 63;
    int b = idx / (56*64);
    int e = r*56 + sxc;
    float hn[4];
    #pragma unroll
    for (int k=0;k<4;k++){
        int g = b*4+k;
        hn[k] = (hsm[(size_t)g*3584 + e] - stats[g*2]) * stats[g*2+1];
    }
    float w9v[9] = {0,0,0,0,0,0,0,0,0};
    #pragma unroll
    for (int c=0;c<16;c++){
        float hv = bc[c];
        #pragma unroll
        for (int k=0;k<4;k++) hv += wc[c*4+k]*hn[k];
        hv = leaky(hv);
        #pragma unroll
        for (int t=0;t<9;t++) w9v[t] += wfl[c*9+t]*hv;
    }
    float* dst = w9g + (((size_t)b*64 + r)*9)*56 + sxc;
    #pragma unroll
    for (int t=0;t<9;t++) dst[t*56] = w9v[t];
}

// ---- kernel 5: out[b,y,x] = leaky(bf + sum_{dy,dx} w9[b][r(y,dy)][dy*3+dx][sx(x,dx)]) ----
__global__ __launch_bounds__(256) void k5_out(const float* __restrict__ w9g, const float* __restrict__ bf,
                                              float* __restrict__ out){
    int x = threadIdx.x;
    int y = blockIdx.x & 255;
    int b = blockIdx.x >> 8;
    const float* wb = w9g + (size_t)b*64*9*56;
    float acc = bf[0];
    int sxm = ((x-1)*7) >> 5;
    int sx0 = (x*7) >> 5;
    int sxp = ((x+1)*7) >> 5;
    #pragma unroll
    for (int dy=0; dy<3; ++dy){
        int yy = y + dy - 1;
        if ((unsigned)yy >= 256u) continue;
        const float* wr = wb + (((yy>>2)*9) + dy*3)*56;
        if (x >= 1)   acc += wr[0*56 + sxm];
                      acc += wr[1*56 + sx0];
        if (x <= 254) acc += wr[2*56 + sxp];
    }
    out[((size_t)(b*256 + y))*256 + x] = leaky(acc);
}

extern "C" void kernel_launch(void* const* d_in, const int* in_sizes, int n_in,
                              void* d_out, int out_size, void* d_ws, size_t ws_size,
                              hipStream_t stream){
    const float* x  = (const float*)d_in[0];
    const float* cl = (const float*)d_in[1];
    const float* ch = (const float*)d_in[2];
    const float* we = (const float*)d_in[3];
    const float* be = (const float*)d_in[4];
    const float* wc = (const float*)d_in[5];
    const float* bc = (const float*)d_in[6];
    const float* wf = (const float*)d_in[7];
    const float* bf = (const float*)d_in[8];
    float* out = (float*)d_out;

    float* s = (float*)d_ws;                          // 16*SBP floats (zero-padded field)
    size_t off = (size_t)BATCH*SBP;
    unsigned* mnk = (unsigned*)(s + off); off += 128;
    unsigned* mxk = (unsigned*)(s + off); off += 128;
    float* hist = s + off; off += 4096;
    float* hsm  = s + off; off += 229376;
    float* stats= s + off; off += 128;
    float* w9g  = s + off; off += (size_t)16*64*9*56;

    k1_pool<<<(BATCH*SBP + 255)/256, 256, 0, stream>>>(x, s, mnk, mxk, hist);
    k2_minmax<<<dim3(32,16), 256, 0, stream>>>(s, cl, ch, mnk, mxk);
    k3_hist<<<dim3(16,16), 256, 0, stream>>>(s, cl, ch, mnk, mxk, hist);
    k4a<<<64, 256, 0, stream>>>(hist, mnk, mxk, we, be, hsm, stats);
    k4w<<<(16*64*56 + 255)/256, 256, 0, stream>>>(hsm, stats, wc, bc, wf, w9g);
    k5_out<<<16*256, 256, 0, stream>>>(w9g, bf, out);
}

// Round 4
// 156.965 us; speedup vs baseline: 1.0409x; 1.0351x over previous
//
#include <hip/hip_runtime.h>
#include <stdint.h>
#include <math.h>

#define HH 256
#define WW 256
#define BATCH 16
#define HP 257            // pooled field is 257x257
#define SROW 264          // padded row stride
#define SH 259            // padded rows (1 zero row top/bottom)
#define SBP (SH*SROW)     // per-batch padded s size = 68376 floats
#define NPIX (HP*HP)      // 66049

__device__ __forceinline__ float leaky(float v){ return v >= 0.f ? v : 0.01f*v; }

__device__ __forceinline__ unsigned fkey(float f){
    unsigned u = __float_as_uint(f);
    return (u & 0x80000000u) ? ~u : (u | 0x80000000u);
}
__device__ __forceinline__ float funkey(unsigned k){
    return (k & 0x80000000u) ? __uint_as_float(k ^ 0x80000000u) : __uint_as_float(~k);
}

// group k (0..3) channel-0 offset; channel 1 uses the negation.
__device__ __forceinline__ void group_off(int k, int& dh, int& dw){
    dh = (k == 3) ? 0 : -1;
    dw = (k == 3) ? 1 : (k - 1);
}

// ---- kernel 1: s_pad[b,ph,pw]; interior = (sum_c 2x2 avgpool)/4, border = 0.
//      block 0 also zero-inits mnk/mxk/hist (stream order => visible to k2/k3). ----
__global__ __launch_bounds__(256) void k1_pool(const float* __restrict__ x, float* __restrict__ s,
                                               unsigned* __restrict__ mnk, unsigned* __restrict__ mxk,
                                               float* __restrict__ hist){
    if (blockIdx.x == 0){
        if (threadIdx.x < 128){ mnk[threadIdx.x] = 0xFFFFFFFFu; mxk[threadIdx.x] = 0u; }
        for (int t = threadIdx.x; t < 4096; t += 256) hist[t] = 0.f;
    }
    int idx = blockIdx.x*256 + threadIdx.x;
    if (idx >= BATCH*SBP) return;
    int b = idx / SBP;
    int r = idx % SBP;
    int ph = r / SROW, pw = r % SROW;
    int h = ph - 1, w = pw - 1;
    float val = 0.f;
    if ((unsigned)h < (unsigned)HP && (unsigned)w < (unsigned)HP){
        const float* xb = x + (size_t)b*3*HH*WW;
        float acc = 0.f;
        #pragma unroll
        for (int dy=-1; dy<=0; ++dy){
            int i = h+dy; if ((unsigned)i >= HH) continue;
            #pragma unroll
            for (int dx=-1; dx<=0; ++dx){
                int j = w+dx; if ((unsigned)j >= WW) continue;
                int o = i*WW + j;
                acc += xb[o] + xb[HH*WW + o] + xb[2*HH*WW + o];
            }
        }
        val = acc * 0.25f;
    }
    s[idx] = val;
}

// ---- kernel 2: min/max per (batch, group, channel). Wave wv handles group wv.
//      clip is monotone => clamp once after the reduction. ----
__global__ __launch_bounds__(256) void k2_minmax(const float* __restrict__ s, const float* __restrict__ cl,
                                                 const float* __restrict__ chp,
                                                 unsigned* __restrict__ mnk, unsigned* __restrict__ mxk){
    int b = blockIdx.y;
    int wv = threadIdx.x >> 6, lane = threadIdx.x & 63;
    int dh, dw; group_off(wv, dh, dw);
    int doff = dh*SROW + dw;
    const float* sp = s + (size_t)b*SBP + SROW + 1;
    float mn0=INFINITY, mx0=-INFINITY, mn1=INFINITY, mx1=-INFINITY;
    for (int idx = blockIdx.x*64 + lane; idx < NPIX; idx += gridDim.x*64){
        int h = idx / HP, w = idx - h*HP;
        const float* p = sp + h*SROW + w;
        float c = p[0];
        float v0 = c - p[doff];
        float v1 = c - p[-doff];
        mn0 = fminf(mn0,v0); mx0 = fmaxf(mx0,v0);
        mn1 = fminf(mn1,v1); mx1 = fmaxf(mx1,v1);
    }
    #pragma unroll
    for (int off=32; off; off>>=1){
        mn0 = fminf(mn0, __shfl_down(mn0, off));
        mx0 = fmaxf(mx0, __shfl_down(mx0, off));
        mn1 = fminf(mn1, __shfl_down(mn1, off));
        mx1 = fmaxf(mx1, __shfl_down(mx1, off));
    }
    if (lane == 0){
        float lo = cl[0], hi = chp[0];
        int g = b*4 + wv;
        atomicMin(&mnk[g*2+0], fkey(fminf(fmaxf(mn0, lo), hi)));
        atomicMax(&mxk[g*2+0], fkey(fminf(fmaxf(mx0, lo), hi)));
        atomicMin(&mnk[g*2+1], fkey(fminf(fmaxf(mn1, lo), hi)));
        atomicMax(&mxk[g*2+1], fkey(fminf(fmaxf(mx1, lo), hi)));
    }
}

// ---- kernel 3: joint histogram. Wave wv handles group wv; 32 LDS replicas/group,
//      replica-minor layout => simultaneous lane atomics hit distinct banks. ----
__global__ __launch_bounds__(256) void k3_hist(const float* __restrict__ s, const float* __restrict__ cl,
                                               const float* __restrict__ chp,
                                               const unsigned* __restrict__ mnk, const unsigned* __restrict__ mxk,
                                               float* __restrict__ hist){
    __shared__ float lh[4*64*32];   // [group][bin][replica] = 32 KB
    int b = blockIdx.y;
    int wv = threadIdx.x >> 6, lane = threadIdx.x & 63;
    for (int t = threadIdx.x; t < 4*64*32; t += 256) lh[t] = 0.f;
    __syncthreads();
    int g = b*4 + wv;
    float lo = cl[0], hi = chp[0];
    float mn0 = funkey(mnk[g*2+0]), mx0 = funkey(mxk[g*2+0]);
    float mn1 = funkey(mnk[g*2+1]), mx1 = funkey(mxk[g*2+1]);
    float cd0 = (mx0-mn0)*0.125f;
    float cd1 = (mx1-mn1)*0.125f;
    float m0[9], m1[9];
    #pragma unroll
    for (int i=0;i<9;i++){
        m0[i] = __fadd_rn(__fmul_rn((float)i, cd0), mn0);   // match ref: mul then add, no fma
        m1[i] = __fadd_rn(__fmul_rn((float)i, cd1), mn1);
    }
    int dh, dw; group_off(wv, dh, dw);
    int doff = dh*SROW + dw;
    const float* sp = s + (size_t)b*SBP + SROW + 1;
    float* lhg = lh + wv*2048 + (lane & 31);
    for (int idx = blockIdx.x*64 + lane; idx < NPIX; idx += gridDim.x*64){
        int h = idx / HP, w = idx - h*HP;
        const float* p = sp + h*SROW + w;
        float c = p[0];
        float v0 = fminf(fmaxf(c - p[doff],  lo), hi);
        float v1 = fminf(fmaxf(c - p[-doff], lo), hi);
        unsigned b0=0, b1=0;
        #pragma unroll
        for (int i=0;i<8;i++){
            b0 |= (v0>=m0[i] && v0<=m0[i+1]) ? (1u<<i) : 0u;  // boundary values hit 2 bins, like ref
            b1 |= (v1>=m1[i] && v1<=m1[i+1]) ? (1u<<i) : 0u;
        }
        float pr = v0*v1;
        unsigned bb0=b0;
        while (bb0){
            int i = __ffs(bb0)-1; bb0 &= bb0-1;
            unsigned bb1=b1;
            while (bb1){
                int j = __ffs(bb1)-1; bb1 &= bb1-1;
                atomicAdd(&lhg[(i*8+j)*32], pr);
            }
        }
    }
    __syncthreads();
    // wave wv reduces its own group's 64 bins; rotated replica start avoids bank conflicts
    float acc = 0.f;
    #pragma unroll
    for (int r=0;r<32;r++) acc += lh[(wv*64 + lane)*32 + ((lane + r)&31)];
    atomicAdd(&hist[g*64 + lane], acc);
}

// ---- kernel 4a: per group (block): hist-sum, expand+leaky -> hsm; weighted LN stats ----
__global__ __launch_bounds__(256) void k4a(const float* __restrict__ hist,
                    const unsigned* __restrict__ mnk, const unsigned* __restrict__ mxk,
                    const float* __restrict__ we, const float* __restrict__ be,
                    float* __restrict__ hsm, float* __restrict__ stats){
    __shared__ float hloc[3584];
    __shared__ float sred[4];
    int g = blockIdx.x;    // 0..63
    int tid = threadIdx.x;
    float ps = 0.f;
    for (int t=tid; t<4096; t+=256) ps += hist[t];
    #pragma unroll
    for (int off=32; off; off>>=1) ps += __shfl_down(ps, off);
    if ((tid&63)==0) sred[tid>>6] = ps;
    __syncthreads();
    float S = sred[0]+sred[1]+sred[2]+sred[3];

    float mn0 = funkey(mnk[g*2+0]), mx0 = funkey(mxk[g*2+0]);
    float mn1 = funkey(mnk[g*2+1]), mx1 = funkey(mxk[g*2+1]);
    float lvl0 = __fadd_rn(__fmul_rn(1.0f,(mx0-mn0)*0.125f), mn0);   // measure[:,1,0]
    float lvl1 = __fadd_rn(__fmul_rn(1.0f,(mx1-mn1)*0.125f), mn1);

    for (int e=tid; e<3584; e+=256){
        int ij = e/56, o = e%56;
        int i = ij>>3, j = ij&7;
        float f0 = __fmul_rn((float)(i+1), lvl0);
        float f1 = __fmul_rn((float)(j+1), lvl1);
        float f2 = hist[g*64+ij] / S;
        float a = f0*we[o*3+0] + f1*we[o*3+1] + f2*we[o*3+2] + be[o];
        a = leaky(a);
        hloc[e] = a;
        hsm[(size_t)g*3584 + e] = a;
    }
    __syncthreads();

    float pm = 0.f;
    for (int e=tid; e<3584; e+=256){
        int o = e%56;
        int lo_ = (32*o+6)/7, hi_ = (32*o+31)/7;
        float wgt = (float)(4*(hi_-lo_+1));
        pm += hloc[e]*wgt;
    }
    #pragma unroll
    for (int off=32; off; off>>=1) pm += __shfl_down(pm, off);
    if ((tid&63)==0) sred[tid>>6]=pm;
    __syncthreads();
    float mean = (sred[0]+sred[1]+sred[2]+sred[3]) * (1.0f/65536.0f);
    __syncthreads();
    float pv = 0.f;
    for (int e=tid; e<3584; e+=256){
        int o = e%56;
        int lo_ = (32*o+6)/7, hi_ = (32*o+31)/7;
        float wgt = (float)(4*(hi_-lo_+1));
        float d = hloc[e]-mean;
        pv += d*d*wgt;
    }
    #pragma unroll
    for (int off=32; off; off>>=1) pv += __shfl_down(pv, off);
    if ((tid&63)==0) sred[tid>>6]=pv;
    __syncthreads();
    float var = (sred[0]+sred[1]+sred[2]+sred[3]) * (1.0f/65536.0f);
    if (tid==0){
        stats[g*2+0] = mean;
        stats[g*2+1] = 1.0f / sqrtf(var + 1e-5f);
    }
}

// ---- kernel 4w: LN + w_conv + leaky + fold with w_final -> w9[b][r][dy*3+dx][s] ----
__global__ __launch_bounds__(256) void k4w(const float* __restrict__ hsm, const float* __restrict__ stats,
                                           const float* __restrict__ wc, const float* __restrict__ bc,
                                           const float* __restrict__ wf,
                                           float* __restrict__ w9g){
    __shared__ float wfl[144];
    if (threadIdx.x < 144) wfl[threadIdx.x] = wf[threadIdx.x];
    __syncthreads();
    int idx = blockIdx.x*256 + threadIdx.x;
    if (idx >= 16*64*56) return;
    int sxc = idx % 56;
    int r = (idx/56) & 63;
    int b = idx / (56*64);
    int e = r*56 + sxc;
    float hn[4];
    #pragma unroll
    for (int k=0;k<4;k++){
        int g = b*4+k;
        hn[k] = (hsm[(size_t)g*3584 + e] - stats[g*2]) * stats[g*2+1];
    }
    float w9v[9] = {0,0,0,0,0,0,0,0,0};
    #pragma unroll
    for (int c=0;c<16;c++){
        float hv = bc[c];
        #pragma unroll
        for (int k=0;k<4;k++) hv += wc[c*4+k]*hn[k];
        hv = leaky(hv);
        #pragma unroll
        for (int t=0;t<9;t++) w9v[t] += wfl[c*9+t]*hv;
    }
    float* dst = w9g + (((size_t)b*64 + r)*9)*56 + sxc;
    #pragma unroll
    for (int t=0;t<9;t++) dst[t*56] = w9v[t];
}

// ---- kernel 5: out[b,y,x] = leaky(bf + sum_{dy,dx} w9[b][r(y,dy)][dy*3+dx][sx(x,dx)]) ----
__global__ __launch_bounds__(256) void k5_out(const float* __restrict__ w9g, const float* __restrict__ bf,
                                              float* __restrict__ out){
    int x = threadIdx.x;
    int y = blockIdx.x & 255;
    int b = blockIdx.x >> 8;
    const float* wb = w9g + (size_t)b*64*9*56;
    float acc = bf[0];
    int sxm = ((x-1)*7) >> 5;
    int sx0 = (x*7) >> 5;
    int sxp = ((x+1)*7) >> 5;
    #pragma unroll
    for (int dy=0; dy<3; ++dy){
        int yy = y + dy - 1;
        if ((unsigned)yy >= 256u) continue;
        const float* wr = wb + (((yy>>2)*9) + dy*3)*56;
        if (x >= 1)   acc += wr[0*56 + sxm];
                      acc += wr[1*56 + sx0];
        if (x <= 254) acc += wr[2*56 + sxp];
    }
    out[((size_t)(b*256 + y))*256 + x] = leaky(acc);
}

extern "C" void kernel_launch(void* const* d_in, const int* in_sizes, int n_in,
                              void* d_out, int out_size, void* d_ws, size_t ws_size,
                              hipStream_t stream){
    const float* x  = (const float*)d_in[0];
    const float* cl = (const float*)d_in[1];
    const float* ch = (const float*)d_in[2];
    const float* we = (const float*)d_in[3];
    const float* be = (const float*)d_in[4];
    const float* wc = (const float*)d_in[5];
    const float* bc = (const float*)d_in[6];
    const float* wf = (const float*)d_in[7];
    const float* bf = (const float*)d_in[8];
    float* out = (float*)d_out;

    float* s = (float*)d_ws;                          // 16*SBP floats (zero-padded field)
    size_t off = (size_t)BATCH*SBP;
    unsigned* mnk = (unsigned*)(s + off); off += 128;
    unsigned* mxk = (unsigned*)(s + off); off += 128;
    float* hist = s + off; off += 4096;
    float* hsm  = s + off; off += 229376;
    float* stats= s + off; off += 128;
    float* w9g  = s + off; off += (size_t)16*64*9*56;

    k1_pool<<<(BATCH*SBP + 255)/256, 256, 0, stream>>>(x, s, mnk, mxk, hist);
    k2_minmax<<<dim3(64,16), 256, 0, stream>>>(s, cl, ch, mnk, mxk);
    k3_hist<<<dim3(64,16), 256, 0, stream>>>(s, cl, ch, mnk, mxk, hist);
    k4a<<<64, 256, 0, stream>>>(hist, mnk, mxk, we, be, hsm, stats);
    k4w<<<(16*64*56 + 255)/256, 256, 0, stream>>>(hsm, stats, wc, bc, wf, w9g);
    k5_out<<<16*256, 256, 0, stream>>>(w9g, bf, out);
}